// Round 3
// baseline (4916.091 us; speedup 1.0000x reference)
//
#include <hip/hip_runtime.h>
#include <math.h>

// GPT-2-small forward: B=4, T=1024, D=768, H=12, HD=64, L=6, FF=3072, V=50257
// GEMMs: bf16 MFMA (fp32 accum), m97 structure. Attention: tiled flash-style,
// fp32 math in LDS, bf16 storage. LN/loss fp32.

#define D_ 768
#define H_ 12
#define HD_ 64
#define L_ 6
#define FF_ 3072
#define V_ 50257
#define VPAD_ 50304   // 393 * 128
#define T_ 1024
#define EPS_ 1e-5f
#define SCALE_ 0.03608439182435161f  // 768^-0.5

typedef unsigned short u16;
typedef __attribute__((ext_vector_type(8))) unsigned short u16x8;
typedef __attribute__((ext_vector_type(4))) float f32x4;
typedef __attribute__((ext_vector_type(8))) __bf16 bf16x8;

__device__ __forceinline__ float b2f(u16 u) {
  union { unsigned int i; float f; } c; c.i = ((unsigned int)u) << 16; return c.f;
}
__device__ __forceinline__ u16 f2b(float f) {
  union { float f; unsigned int i; } c; c.f = f;
  unsigned int r = c.i + 0x7fffu + ((c.i >> 16) & 1u);  // RNE
  return (u16)(r >> 16);
}

// ---------------------------------------------------------------- reductions
__device__ __forceinline__ float waveReduceSum(float v) {
#pragma unroll
  for (int o = 32; o > 0; o >>= 1) v += __shfl_down(v, o, 64);
  return v;
}
__device__ __forceinline__ float waveReduceMax(float v) {
#pragma unroll
  for (int o = 32; o > 0; o >>= 1) v = fmaxf(v, __shfl_down(v, o, 64));
  return v;
}
__device__ __forceinline__ float blockReduceSum(float v, float* red) {
  int lane = threadIdx.x & 63, w = threadIdx.x >> 6;
  v = waveReduceSum(v);
  if (lane == 0) red[w] = v;
  __syncthreads();
  float r = red[0] + red[1] + red[2] + red[3];
  __syncthreads();
  return r;
}
__device__ __forceinline__ float blockReduceMax(float v, float* red) {
  int lane = threadIdx.x & 63, w = threadIdx.x >> 6;
  v = waveReduceMax(v);
  if (lane == 0) red[w] = v;
  __syncthreads();
  float r = fmaxf(fmaxf(red[0], red[1]), fmaxf(red[2], red[3]));
  __syncthreads();
  return r;
}

// ---------------------------------------------------------------- embedding
__global__ __launch_bounds__(256) void embed_kernel(
    const int* __restrict__ idx, const float* __restrict__ tok,
    const float* __restrict__ pos, float* __restrict__ x, int BT) {
  const int nD4 = D_ / 4;
  int i = blockIdx.x * blockDim.x + threadIdx.x;
  if (i >= BT * nD4) return;
  int row = i / nD4, d4 = i - row * nD4;
  int t = row & (T_ - 1);
  int token = idx[row];
  float4 a = *reinterpret_cast<const float4*>(tok + (size_t)token * D_ + d4 * 4);
  float4 b = *reinterpret_cast<const float4*>(pos + (size_t)t * D_ + d4 * 4);
  float4 o;
  o.x = a.x + b.x; o.y = a.y + b.y; o.z = a.z + b.z; o.w = a.w + b.w;
  *reinterpret_cast<float4*>(x + (size_t)i * 4) = o;
}

// ---------------------------------------------------------------- layernorm
// one block (256 threads) per row of 768; fp32 in, bf16 out
__global__ __launch_bounds__(256) void ln_kernel(
    const float* __restrict__ x, u16* __restrict__ y,
    const float* __restrict__ s, const float* __restrict__ b) {
  __shared__ float red[4];
  int row = blockIdx.x;
  const float* px = x + (size_t)row * D_;
  int tid = threadIdx.x;
  float v0 = px[tid], v1 = px[tid + 256], v2 = px[tid + 512];
  float sum = blockReduceSum(v0 + v1 + v2, red);
  float mean = sum * (1.0f / D_);
  float d0 = v0 - mean, d1 = v1 - mean, d2 = v2 - mean;
  float vs = blockReduceSum(d0 * d0 + d1 * d1 + d2 * d2, red);
  float rs = rsqrtf(vs * (1.0f / D_) + EPS_);
  u16* py = y + (size_t)row * D_;
  py[tid]       = f2b(d0 * rs * s[tid]       + b[tid]);
  py[tid + 256] = f2b(d1 * rs * s[tid + 256] + b[tid + 256]);
  py[tid + 512] = f2b(d2 * rs * s[tid + 512] + b[tid + 512]);
}

// ---------------------------------------------------------------- transpose+convert
// W fp32 [K][N] -> WT bf16 [Npad][K], zero-filled rows n in [N, Npad)
__global__ __launch_bounds__(256) void transpose_convert(
    const float* __restrict__ W, u16* __restrict__ WT, int K, int N, int Npad) {
  __shared__ float tile[32][33];
  int n0 = blockIdx.x * 32, k0 = blockIdx.y * 32;
  int tx = threadIdx.x & 31, ty = threadIdx.x >> 5;  // ty 0..7
#pragma unroll
  for (int r = 0; r < 32; r += 8) {
    int k = k0 + ty + r, n = n0 + tx;
    tile[ty + r][tx] = (n < N) ? W[(size_t)k * N + n] : 0.f;  // K is mult of 32
  }
  __syncthreads();
#pragma unroll
  for (int r = 0; r < 32; r += 8) {
    int n = n0 + ty + r, k = k0 + tx;
    WT[(size_t)n * K + k] = f2b(tile[tx][ty + r]);
  }
}

// ---------------------------------------------------------------- bf16 MFMA GEMM
// C[M,N] = A[M,K](bf16) @ Bt[N,K]^T(bf16)  (+bias) (+relu) (accum fp32 / bf16 out)
// 128x128 tile, BK=32, 256 threads (4 waves as 2x2 of 64x64), m97 structure.
template <bool RELU, bool ACCUM, bool BF16OUT>
__global__ __launch_bounds__(256) void bgemm_kernel(
    const u16* __restrict__ A,
    const u16* __restrict__ Bt0, const u16* __restrict__ Bt1, const u16* __restrict__ Bt2,
    float* __restrict__ Cf0, float* __restrict__ Cf1, float* __restrict__ Cf2,
    u16* __restrict__ Ch0, u16* __restrict__ Ch1, u16* __restrict__ Ch2,
    const float* __restrict__ bias0, const float* __restrict__ bias1, const float* __restrict__ bias2,
    int M, int N, int K, int ldc) {
  const u16* Bt   = blockIdx.z == 0 ? Bt0   : (blockIdx.z == 1 ? Bt1   : Bt2);
  float* Cf       = blockIdx.z == 0 ? Cf0   : (blockIdx.z == 1 ? Cf1   : Cf2);
  u16* Ch         = blockIdx.z == 0 ? Ch0   : (blockIdx.z == 1 ? Ch1   : Ch2);
  const float* bias = blockIdx.z == 0 ? bias0 : (blockIdx.z == 1 ? bias1 : bias2);

  __shared__ u16 As[128 * 32];
  __shared__ u16 Bs[128 * 32];

  const int tid = threadIdx.x;
  const int wave = tid >> 6, lane = tid & 63;
  const int wm = wave >> 1, wn = wave & 1;
  const int bm = blockIdx.y * 128, bn = blockIdx.x * 128;

  f32x4 acc[4][4] = {};

  const int r0 = tid >> 2;         // staging row within 64-row half
  const int kk0 = (tid & 3) << 3;  // staging k-offset (8 elems = 16 B)
  const int lr = lane & 15, lk = (lane >> 4) << 3;

  for (int k0 = 0; k0 < K; k0 += 32) {
#pragma unroll
    for (int c = 0; c < 2; ++c) {
      int row = c * 64 + r0;
      const u16* ga = A  + (size_t)(bm + row) * K + k0 + kk0;
      const u16* gb = Bt + (size_t)(bn + row) * K + k0 + kk0;
      // LDS dest: wave-uniform base; HW adds lane*16 bytes.
      u16* la = As + c * 2048 + wave * 512;
      u16* lb = Bs + c * 2048 + wave * 512;
      __builtin_amdgcn_global_load_lds((const __attribute__((address_space(1))) void*)ga,
                                       (__attribute__((address_space(3))) void*)la, 16, 0, 0);
      __builtin_amdgcn_global_load_lds((const __attribute__((address_space(1))) void*)gb,
                                       (__attribute__((address_space(3))) void*)lb, 16, 0, 0);
    }
    __syncthreads();  // drains vmcnt; tiles ready

    bf16x8 af[4], bfr[4];
#pragma unroll
    for (int m = 0; m < 4; ++m)
      af[m] = *(const bf16x8*)(As + (wm * 64 + m * 16 + lr) * 32 + lk);
#pragma unroll
    for (int n = 0; n < 4; ++n)
      bfr[n] = *(const bf16x8*)(Bs + (wn * 64 + n * 16 + lr) * 32 + lk);
#pragma unroll
    for (int m = 0; m < 4; ++m)
#pragma unroll
      for (int n = 0; n < 4; ++n)
        acc[m][n] = __builtin_amdgcn_mfma_f32_16x16x32_bf16(af[m], bfr[n], acc[m][n], 0, 0, 0);
    __syncthreads();  // protect LDS before next staging
  }

  // epilogue: C/D layout col=lane&15, row=(lane>>4)*4+reg  [m89-verified]
  const int ecol = lane & 15;
  const int erow = (lane >> 4) << 2;
#pragma unroll
  for (int n = 0; n < 4; ++n) {
    int col = bn + wn * 64 + n * 16 + ecol;
    if (col < N) {
      float bv = bias ? bias[col] : 0.f;
#pragma unroll
      for (int m = 0; m < 4; ++m) {
        int rowb = bm + wm * 64 + m * 16 + erow;
#pragma unroll
        for (int r = 0; r < 4; ++r) {
          float v = acc[m][n][r] + bv;
          if (RELU) v = fmaxf(v, 0.f);
          size_t ci = (size_t)(rowb + r) * ldc + col;
          if (BF16OUT) Ch[ci] = f2b(v);
          else if (ACCUM) Cf[ci] += v;
          else Cf[ci] = v;
        }
      }
    }
  }
}

// ---------------------------------------------------------------- attention
// Tiled flash-style: one block per (b, h, 64-row Q tile). 256 threads:
// thread = (ql = tid&63: q row, g = tid>>6: 16-dim / 16-s slice).
// K/V staged per 64-row s-tile into LDS as fp32; online softmax in regs.
__global__ __launch_bounds__(256) void attn_tiled_kernel(
    const u16* __restrict__ q, const u16* __restrict__ k,
    const u16* __restrict__ v, u16* __restrict__ out) {
  __shared__ float Qs[64][68];   // q rows, pre-scaled
  __shared__ float Ks[64][68];
  __shared__ float Vs[64][68];
  __shared__ float Ss[64][68];   // scores -> exp weights
  __shared__ float redm[64][4];
  __shared__ float reds[64][4];

  const int qt = blockIdx.x;
  const int bh = blockIdx.y;
  const int h = bh % H_;
  const int b = bh / H_;
  const int tid = threadIdx.x;
  const int ql = tid & 63;
  const int g  = tid >> 6;

  const int sr  = tid >> 2;         // staging row 0..63
  const int sc0 = (tid & 3) * 16;   // staging col offset

  // stage Q tile (scaled by 768^-0.5)
  {
    const u16* gq = q + ((size_t)(b * T_ + qt * 64 + sr)) * D_ + h * HD_ + sc0;
    u16x8 a = *(const u16x8*)gq;
    u16x8 c = *(const u16x8*)(gq + 8);
#pragma unroll
    for (int j = 0; j < 8; ++j) Qs[sr][sc0 + j]     = b2f(a[j]) * SCALE_;
#pragma unroll
    for (int j = 0; j < 8; ++j) Qs[sr][sc0 + 8 + j] = b2f(c[j]) * SCALE_;
  }

  float O[16];
#pragma unroll
  for (int i = 0; i < 16; ++i) O[i] = 0.f;
  float mrow = -3.0e38f, lrow = 0.f;

  for (int st = 0; st <= qt; ++st) {
    __syncthreads();  // prev readers done (also: Q staged, first iter)
    {
      const size_t base = ((size_t)(b * T_ + st * 64 + sr)) * D_ + h * HD_ + sc0;
      u16x8 ka = *(const u16x8*)(k + base);
      u16x8 kb2 = *(const u16x8*)(k + base + 8);
      u16x8 va = *(const u16x8*)(v + base);
      u16x8 vb2 = *(const u16x8*)(v + base + 8);
#pragma unroll
      for (int j = 0; j < 8; ++j) { Ks[sr][sc0 + j] = b2f(ka[j]); Ks[sr][sc0 + 8 + j] = b2f(kb2[j]); }
#pragma unroll
      for (int j = 0; j < 8; ++j) { Vs[sr][sc0 + j] = b2f(va[j]); Vs[sr][sc0 + 8 + j] = b2f(vb2[j]); }
    }
    __syncthreads();

    // QK^T: 16 scores for s in [g*16, g*16+16). K reads are wave-broadcast.
    float sloc[16];
#pragma unroll
    for (int i = 0; i < 16; ++i) sloc[i] = 0.f;
    for (int j = 0; j < 64; j += 4) {
      float4 qv = *(const float4*)&Qs[ql][j];
#pragma unroll
      for (int i = 0; i < 16; ++i) {
        float4 kv = *(const float4*)&Ks[g * 16 + i][j];
        sloc[i] += qv.x * kv.x + qv.y * kv.y + qv.z * kv.z + qv.w * kv.w;
      }
    }

    const bool diag = (st == qt);
    float lmax = -3.0e38f;
#pragma unroll
    for (int i = 0; i < 16; ++i) {
      int s = g * 16 + i;
      if (diag && s > ql) sloc[i] = -3.0e38f;
      lmax = fmaxf(lmax, sloc[i]);
    }
    redm[ql][g] = lmax;
    __syncthreads();

    float mtile = fmaxf(fmaxf(redm[ql][0], redm[ql][1]), fmaxf(redm[ql][2], redm[ql][3]));
    float mnew = fmaxf(mrow, mtile);
    float scale = __expf(mrow - mnew);
    float lsum = 0.f;
#pragma unroll
    for (int i = 0; i < 16; ++i) {
      float e = __expf(sloc[i] - mnew);
      Ss[ql][g * 16 + i] = e;
      lsum += e;
    }
    reds[ql][g] = lsum;
#pragma unroll
    for (int i = 0; i < 16; ++i) O[i] *= scale;
    mrow = mnew;
    __syncthreads();
    lrow = lrow * scale + reds[ql][0] + reds[ql][1] + reds[ql][2] + reds[ql][3];

    // PV: O[dd] += sum_s e[s] * V[s][g*16+dd]. V reads wave-broadcast.
    for (int s = 0; s < 64; s += 4) {
      float4 ev = *(const float4*)&Ss[ql][s];
#pragma unroll
      for (int u = 0; u < 4; ++u) {
        float e = (u == 0) ? ev.x : (u == 1) ? ev.y : (u == 2) ? ev.z : ev.w;
        float4 v0 = *(const float4*)&Vs[s + u][g * 16 + 0];
        float4 v1 = *(const float4*)&Vs[s + u][g * 16 + 4];
        float4 v2 = *(const float4*)&Vs[s + u][g * 16 + 8];
        float4 v3 = *(const float4*)&Vs[s + u][g * 16 + 12];
        O[0]  += e * v0.x; O[1]  += e * v0.y; O[2]  += e * v0.z; O[3]  += e * v0.w;
        O[4]  += e * v1.x; O[5]  += e * v1.y; O[6]  += e * v1.z; O[7]  += e * v1.w;
        O[8]  += e * v2.x; O[9]  += e * v2.y; O[10] += e * v2.z; O[11] += e * v2.w;
        O[12] += e * v3.x; O[13] += e * v3.y; O[14] += e * v3.z; O[15] += e * v3.w;
      }
    }
  }

  float inv = 1.0f / lrow;
  u16x8 o0, o1;
#pragma unroll
  for (int i = 0; i < 8; ++i) o0[i] = f2b(O[i] * inv);
#pragma unroll
  for (int i = 0; i < 8; ++i) o1[i] = f2b(O[8 + i] * inv);
  u16* po = out + ((size_t)(b * T_ + qt * 64 + ql)) * D_ + h * HD_ + g * 16;
  *(u16x8*)po = o0;
  *(u16x8*)(po + 8) = o1;
}

// ---------------------------------------------------------------- loss
__global__ __launch_bounds__(256) void loss_rows_kernel(
    const float* __restrict__ logits, const int* __restrict__ targets,
    float* __restrict__ rowloss) {
  __shared__ float redm[4], reds[4];
  int row = blockIdx.x;
  const float* p = logits + (size_t)row * V_;
  int tid = threadIdx.x;
  float m = -INFINITY, s = 0.f;
  for (int j = tid; j < V_; j += 256) {
    float x = p[j];
    if (x > m) {
      s = s * expf(m - x) + 1.0f;
      m = x;
    } else {
      s += expf(x - m);
    }
  }
  float bm = blockReduceMax(m, redm);
  s *= expf(m - bm);
  float bs = blockReduceSum(s, reds);
  if (tid == 0) {
    float lse = bm + logf(bs);
    rowloss[row] = lse - p[targets[row]];
  }
}

__global__ __launch_bounds__(256) void loss_final_kernel(
    const float* __restrict__ rowloss, int n, float* __restrict__ out) {
  __shared__ float red[4];
  int tid = threadIdx.x;
  float s = 0.f;
  for (int i = tid; i < n; i += 256) s += rowloss[i];
  s = blockReduceSum(s, red);
  if (tid == 0) out[0] = s / n;
}

// ---------------------------------------------------------------- launch
extern "C" void kernel_launch(void* const* d_in, const int* in_sizes, int n_in,
                              void* d_out, int out_size, void* d_ws, size_t ws_size,
                              hipStream_t stream) {
  const int* idx      = (const int*)d_in[0];
  const int* targets  = (const int*)d_in[1];
  const float* tok    = (const float*)d_in[2];
  const float* pos    = (const float*)d_in[3];
  const float* ln1_s  = (const float*)d_in[4];
  const float* ln1_b  = (const float*)d_in[5];
  const float* wq     = (const float*)d_in[6];
  const float* wk     = (const float*)d_in[7];
  const float* wv     = (const float*)d_in[8];
  const float* wo     = (const float*)d_in[9];
  const float* bo     = (const float*)d_in[10];
  const float* ln2_s  = (const float*)d_in[11];
  const float* ln2_b  = (const float*)d_in[12];
  const float* w1     = (const float*)d_in[13];
  const float* b1     = (const float*)d_in[14];
  const float* w2     = (const float*)d_in[15];
  const float* b2     = (const float*)d_in[16];
  const float* lnf_s  = (const float*)d_in[17];
  const float* lnf_b  = (const float*)d_in[18];
  const float* lm_w   = (const float*)d_in[19];
  const float* lm_b   = (const float*)d_in[20];

  const int BT = in_sizes[0];   // 4096
  const int Bb = BT / T_;
  const int GM = BT / 128;      // 32

  char* p = (char*)d_ws;
  auto alloc = [&](size_t bytes) -> void* {
    void* r = (void*)p;
    p += (bytes + 255) & ~(size_t)255;
    return r;
  };
  float* x   = (float*)alloc((size_t)BT * D_ * 4);
  u16* hbf   = (u16*)alloc((size_t)BT * D_ * 2);
  u16* qb    = (u16*)alloc((size_t)BT * D_ * 2);
  u16* kb    = (u16*)alloc((size_t)BT * D_ * 2);
  u16* vb    = (u16*)alloc((size_t)BT * D_ * 2);
  u16* ab    = (u16*)alloc((size_t)BT * D_ * 2);
  u16* hid   = (u16*)alloc((size_t)BT * FF_ * 2);
  u16* wqt   = (u16*)alloc((size_t)D_ * D_ * 2);
  u16* wkt   = (u16*)alloc((size_t)D_ * D_ * 2);
  u16* wvt   = (u16*)alloc((size_t)D_ * D_ * 2);
  u16* wot   = (u16*)alloc((size_t)D_ * D_ * 2);
  u16* w1t   = (u16*)alloc((size_t)D_ * FF_ * 2);
  u16* w2t   = (u16*)alloc((size_t)FF_ * D_ * 2);
  u16* lmwt  = (u16*)alloc((size_t)VPAD_ * D_ * 2);
  float* rowloss = (float*)alloc((size_t)BT * 4);

  float* logits = (float*)d_out;
  float* lossp  = logits + (size_t)BT * V_;

  float* fnull = nullptr;
  u16* hnull = nullptr;

  // embedding
  {
    int n4 = BT * (D_ / 4);
    embed_kernel<<<(n4 + 255) / 256, 256, 0, stream>>>(idx, tok, pos, x, BT);
  }
  // lm_w -> bf16 [VPAD_][768]
  transpose_convert<<<dim3(VPAD_ / 32, D_ / 32), 256, 0, stream>>>(lm_w, lmwt, D_, V_, VPAD_);

  for (int l = 0; l < L_; ++l) {
    transpose_convert<<<dim3(D_ / 32, D_ / 32), 256, 0, stream>>>(wq + (size_t)l * D_ * D_, wqt, D_, D_, D_);
    transpose_convert<<<dim3(D_ / 32, D_ / 32), 256, 0, stream>>>(wk + (size_t)l * D_ * D_, wkt, D_, D_, D_);
    transpose_convert<<<dim3(D_ / 32, D_ / 32), 256, 0, stream>>>(wv + (size_t)l * D_ * D_, wvt, D_, D_, D_);
    transpose_convert<<<dim3(D_ / 32, D_ / 32), 256, 0, stream>>>(wo + (size_t)l * D_ * D_, wot, D_, D_, D_);
    transpose_convert<<<dim3(FF_ / 32, D_ / 32), 256, 0, stream>>>(w1 + (size_t)l * D_ * FF_, w1t, D_, FF_, FF_);
    transpose_convert<<<dim3(D_ / 32, FF_ / 32), 256, 0, stream>>>(w2 + (size_t)l * FF_ * D_, w2t, FF_, D_, D_);

    // LN1 -> bf16
    ln_kernel<<<BT, 256, 0, stream>>>(x, hbf, ln1_s + l * D_, ln1_b + l * D_);
    // QKV (no bias) -> bf16
    bgemm_kernel<false, false, true><<<dim3(D_ / 128, GM, 3), 256, 0, stream>>>(
        hbf, wqt, wkt, wvt, fnull, fnull, fnull, qb, kb, vb,
        fnull, fnull, fnull, BT, D_, D_, D_);
    // attention (tiled flash-style)
    attn_tiled_kernel<<<dim3(T_ / 64, Bb * H_), 256, 0, stream>>>(qb, kb, vb, ab);
    // x += att @ Wo + bo
    bgemm_kernel<false, true, false><<<dim3(D_ / 128, GM, 1), 256, 0, stream>>>(
        ab, wot, wot, wot, x, x, x, hnull, hnull, hnull,
        bo + (size_t)l * D_, fnull, fnull, BT, D_, D_, D_);
    // LN2 -> bf16
    ln_kernel<<<BT, 256, 0, stream>>>(x, hbf, ln2_s + l * D_, ln2_b + l * D_);
    // hid = relu(hbf @ W1 + b1) -> bf16
    bgemm_kernel<true, false, true><<<dim3(FF_ / 128, GM, 1), 256, 0, stream>>>(
        hbf, w1t, w1t, w1t, fnull, fnull, fnull, hid, hid, hid,
        b1 + (size_t)l * FF_, fnull, fnull, BT, FF_, D_, FF_);
    // x += hid @ W2 + b2
    bgemm_kernel<false, true, false><<<dim3(D_ / 128, GM, 1), 256, 0, stream>>>(
        hid, w2t, w2t, w2t, x, x, x, hnull, hnull, hnull,
        b2 + (size_t)l * D_, fnull, fnull, BT, D_, FF_, D_);
  }

  // final LN -> bf16
  ln_kernel<<<BT, 256, 0, stream>>>(x, hbf, lnf_s, lnf_b);
  // logits = hbf @ lm_w + lm_b (fp32 out, ldc = V_)
  bgemm_kernel<false, false, false><<<dim3(VPAD_ / 128, GM, 1), 256, 0, stream>>>(
      hbf, lmwt, lmwt, lmwt, logits, logits, logits, hnull, hnull, hnull,
      lm_b, fnull, fnull, BT, V_, D_, V_);
  // loss
  loss_rows_kernel<<<BT, 256, 0, stream>>>(logits, targets, rowloss);
  loss_final_kernel<<<1, 256, 0, stream>>>(rowloss, BT, lossp);
}